// Round 1
// baseline (67.000 us; speedup 1.0000x reference)
//
#include <hip/hip_runtime.h>

// VAR flex-attention, MI355X gfx950.
// Mask (same_doc | causal) == "attend to all keys j < block_end(q)" since
// blocks are contiguous: [0,i] ∪ [start(i),end(i)) = [0, end(i)).
// Flash attention, bf16 MFMA 16x16x32, swapped QK^T (S^T layout) so the
// P fragments feed PV with zero cross-lane movement.

typedef float  f32x4 __attribute__((ext_vector_type(4)));
typedef short  s16x8 __attribute__((ext_vector_type(8)));
typedef short  s16x4 __attribute__((ext_vector_type(4)));

#define L_TOK 680
#define DHEAD 64
#define QBLK  64
#define KVBLK 32
#define VTS   36   // V^T LDS row stride (shorts): 32 + 4 pad

__device__ __forceinline__ int kv_len(int q) {
  // block ends: 1,5,14,30,55,91,155,255,424,680
  return q < 1 ? 1 : q < 5 ? 5 : q < 14 ? 14 : q < 30 ? 30 : q < 55 ? 55
       : q < 91 ? 91 : q < 155 ? 155 : q < 255 ? 255 : q < 424 ? 424 : L_TOK;
}

__device__ __forceinline__ short f2bf(float x) {   // RNE f32 -> bf16 bits
  unsigned u = __float_as_uint(x);
  return (short)((u + 0x7FFFu + ((u >> 16) & 1u)) >> 16);
}

__device__ __forceinline__ s16x8 cvt8(f32x4 a, f32x4 b, float sc) {
  s16x8 f;
  f[0] = f2bf(a[0] * sc); f[1] = f2bf(a[1] * sc);
  f[2] = f2bf(a[2] * sc); f[3] = f2bf(a[3] * sc);
  f[4] = f2bf(b[0] * sc); f[5] = f2bf(b[1] * sc);
  f[6] = f2bf(b[2] * sc); f[7] = f2bf(b[3] * sc);
  return f;
}

__global__ __launch_bounds__(256, 2) void var_attn(
    const float* __restrict__ Qg, const float* __restrict__ Kg,
    const float* __restrict__ Vg, float* __restrict__ Og)
{
  const int tid  = threadIdx.x;
  const int bh   = blockIdx.y;                 // 0..127
  const int qblk = blockIdx.x * QBLK;
  const int wave = tid >> 6;
  const int lane = tid & 63;
  const int l15  = lane & 15;
  const int lg   = lane >> 4;                  // 0..3

  __shared__ short kbuf[KVBLK * DHEAD];        // row-major bf16, XOR-swizzled
  __shared__ short vtbuf[DHEAD * VTS];         // V^T [d][kv], stride VTS

  const int qw   = qblk + wave * 16;           // wave's first query
  const int qrow = qw + l15;                   // this lane's score-query
  const int qc   = min(qrow, L_TOK - 1);
  const int my_kvlen  = kv_len(qc);
  const int kv_need_w = kv_len(min(qw + 15, L_TOK - 1));   // wave-uniform
  const int nkv       = kv_len(min(qblk + QBLK - 1, L_TOK - 1)); // block-uniform

  // ---- load Q fragments (pre-scaled by 1/sqrt(D)) ----
  s16x8 qfrag[2];
  {
    const float* qptr = Qg + ((size_t)(bh * L_TOK + qc)) * DHEAD + lg * 8;
    #pragma unroll
    for (int ks = 0; ks < 2; ++ks) {
      f32x4 a = *(const f32x4*)(qptr + ks * 32);
      f32x4 b = *(const f32x4*)(qptr + ks * 32 + 4);
      qfrag[ks] = cvt8(a, b, 0.125f);
    }
  }

  f32x4 oacc[4] = {};                          // O accum: dt tiles of 16 d
  float m_run = -1e30f, l_run = 0.0f;

  const int stage_r = tid >> 3;                // 0..31 kv row
  const int stage_c = (tid & 7) * 8;           // 0..56 d col
  const float* kbase = Kg + (size_t)bh * L_TOK * DHEAD;
  const float* vbase = Vg + (size_t)bh * L_TOK * DHEAD;

  for (int kv0 = 0; kv0 < nkv; kv0 += KVBLK) {
    // ---- stage K (swizzled row-major) and V^T into LDS ----
    {
      const int rsrc = min(kv0 + stage_r, L_TOK - 1);
      const float* ks_ = kbase + (size_t)rsrc * DHEAD + stage_c;
      f32x4 a = *(const f32x4*)ks_;
      f32x4 b = *(const f32x4*)(ks_ + 4);
      s16x8 kf = cvt8(a, b, 1.0f);
      int boff = (stage_r * 128 + stage_c * 2) ^ ((stage_r & 7) << 4);
      *(s16x8*)((char*)kbuf + boff) = kf;

      const float* vs_ = vbase + (size_t)rsrc * DHEAD + stage_c;
      f32x4 c = *(const f32x4*)vs_;
      f32x4 d = *(const f32x4*)(vs_ + 4);
      #pragma unroll
      for (int i = 0; i < 4; ++i)
        vtbuf[(stage_c + i) * VTS + stage_r] = f2bf(c[i]);
      #pragma unroll
      for (int i = 0; i < 4; ++i)
        vtbuf[(stage_c + 4 + i) * VTS + stage_r] = f2bf(d[i]);
    }
    __syncthreads();

    if (kv0 < kv_need_w) {                     // wave-uniform skip
      // ---- QK^T (swapped): S^T[key][q] ----
      f32x4 sacc[2] = {};
      #pragma unroll
      for (int t = 0; t < 2; ++t) {
        const int kr = t * 16 + l15;
        #pragma unroll
        for (int ks = 0; ks < 2; ++ks) {
          int boff = (kr * 128 + (lg * 8 + ks * 32) * 2) ^ ((kr & 7) << 4);
          s16x8 kf = *(const s16x8*)((char*)kbuf + boff);
          sacc[t] = __builtin_amdgcn_mfma_f32_16x16x32_bf16(kf, qfrag[ks], sacc[t], 0, 0, 0);
        }
      }

      // ---- mask + online softmax (per lane: 8 keys of one query) ----
      float s[8];
      #pragma unroll
      for (int t = 0; t < 2; ++t)
        #pragma unroll
        for (int r = 0; r < 4; ++r) {
          int key = kv0 + t * 16 + lg * 4 + r;
          s[t * 4 + r] = (key < my_kvlen) ? sacc[t][r] : -1e30f;
        }
      float mt = s[0];
      #pragma unroll
      for (int i = 1; i < 8; ++i) mt = fmaxf(mt, s[i]);
      mt = fmaxf(mt, __shfl_xor(mt, 16));
      mt = fmaxf(mt, __shfl_xor(mt, 32));
      float m_new = fmaxf(m_run, mt);
      float sc = __expf(m_run - m_new);
      float psum = 0.0f;
      short pf[8];
      #pragma unroll
      for (int i = 0; i < 8; ++i) {
        float p = __expf(s[i] - m_new);
        psum += p;
        pf[i] = f2bf(p);
      }
      psum += __shfl_xor(psum, 16);
      psum += __shfl_xor(psum, 32);
      l_run = l_run * sc + psum;
      m_run = m_new;

      // ---- rescale O (O rows are q = qw + 4*lg + r; fetch per-row scale) ----
      float sc_q[4];
      #pragma unroll
      for (int r = 0; r < 4; ++r) sc_q[r] = __shfl(sc, lg * 4 + r);
      #pragma unroll
      for (int dt = 0; dt < 4; ++dt)
        #pragma unroll
        for (int r = 0; r < 4; ++r) oacc[dt][r] *= sc_q[r];

      // ---- PV: A = P (from sacc layout directly), B = V via V^T rows ----
      s16x8 pfrag;
      #pragma unroll
      for (int i = 0; i < 8; ++i) pfrag[i] = pf[i];
      #pragma unroll
      for (int dt = 0; dt < 4; ++dt) {
        const short* row = vtbuf + (dt * 16 + l15) * VTS + lg * 4;
        s16x4 v0 = *(const s16x4*)row;
        s16x4 v1 = *(const s16x4*)(row + 16);
        s16x8 vf;
        vf[0] = v0[0]; vf[1] = v0[1]; vf[2] = v0[2]; vf[3] = v0[3];
        vf[4] = v1[0]; vf[5] = v1[1]; vf[6] = v1[2]; vf[7] = v1[3];
        oacc[dt] = __builtin_amdgcn_mfma_f32_16x16x32_bf16(pfrag, vf, oacc[dt], 0, 0, 0);
      }
    }
    __syncthreads();
  }

  // ---- epilogue: normalize and store ----
  float linv = 1.0f / l_run;
  float li_q[4];
  #pragma unroll
  for (int r = 0; r < 4; ++r) li_q[r] = __shfl(linv, lg * 4 + r);
  #pragma unroll
  for (int r = 0; r < 4; ++r) {
    int qo = qw + lg * 4 + r;
    if (qo < L_TOK) {
      float* dst = Og + ((size_t)(bh * L_TOK + qo)) * DHEAD + l15;
      #pragma unroll
      for (int dt = 0; dt < 4; ++dt) dst[dt * 16] = oacc[dt][r] * li_q[r];
    }
  }
}

extern "C" void kernel_launch(void* const* d_in, const int* in_sizes, int n_in,
                              void* d_out, int out_size, void* d_ws, size_t ws_size,
                              hipStream_t stream) {
  const float* q = (const float*)d_in[0];
  const float* k = (const float*)d_in[1];
  const float* v = (const float*)d_in[2];
  float* o = (float*)d_out;
  dim3 grid((L_TOK + QBLK - 1) / QBLK, 128);
  var_attn<<<grid, 256, 0, stream>>>(q, k, v, o);
}

// Round 2
// 53.885 us; speedup vs baseline: 1.2434x; 1.2434x over previous
//
#include <hip/hip_runtime.h>

// VAR flex-attention, MI355X gfx950. Mask == "q attends to keys [0, block_end(q))".
// R2: bf16 prepass (pre-swizzled K rows, V^T chunk-swizzled) into d_ws;
// main kernel: KVBLK=64, global_load_lds(16B) double-buffer, counted vmcnt,
// raw s_barrier, defer-max, XCD-aware block remap. Fallback: R1 kernel.

typedef float  f32x4 __attribute__((ext_vector_type(4)));
typedef short  s16x8 __attribute__((ext_vector_type(8)));
typedef short  s16x4 __attribute__((ext_vector_type(4)));
typedef unsigned int u32;

#define L_TOK 680
#define LPAD  704
#define DHEAD 64
#define QBLK  64
#define NBH   128

__device__ __forceinline__ int kv_len(int q) {
  // block ends: 1,5,14,30,55,91,155,255,424,680
  return q < 1 ? 1 : q < 5 ? 5 : q < 14 ? 14 : q < 30 ? 30 : q < 55 ? 55
       : q < 91 ? 91 : q < 155 ? 155 : q < 255 ? 255 : q < 424 ? 424 : L_TOK;
}

__device__ __forceinline__ short f2bf(float x) {   // RNE f32 -> bf16 bits
  unsigned u = __float_as_uint(x);
  return (short)((u + 0x7FFFu + ((u >> 16) & 1u)) >> 16);
}

__device__ __forceinline__ s16x8 cvt8(f32x4 a, f32x4 b, float sc) {
  s16x8 f;
  f[0] = f2bf(a[0] * sc); f[1] = f2bf(a[1] * sc);
  f[2] = f2bf(a[2] * sc); f[3] = f2bf(a[3] * sc);
  f[4] = f2bf(b[0] * sc); f[5] = f2bf(b[1] * sc);
  f[6] = f2bf(b[2] * sc); f[7] = f2bf(b[3] * sc);
  return f;
}

__device__ __forceinline__ void gload16(const void* g, void* l) {
  __builtin_amdgcn_global_load_lds(
      (const __attribute__((address_space(1))) u32*)g,
      (__attribute__((address_space(3))) u32*)l, 16, 0, 0);
}

// ---------------- prepass K: f32 [bh][680][64] -> bf16 [bh][704][64],
// within-row 16B chunks stored at c ^ (r&7); pad rows zeroed. ----------------
__global__ __launch_bounds__(256) void prep_k(const float* __restrict__ Kg,
                                              short* __restrict__ Ks) {
  int g  = blockIdx.x * 256 + threadIdx.x;       // 128*704*8 threads
  int bh = g / (LPAD * 8);
  int rem = g - bh * (LPAD * 8);
  int r = rem >> 3, c = rem & 7;
  s16x8 o = (s16x8)0;
  if (r < L_TOK) {
    const float* src = Kg + ((size_t)(bh * L_TOK + r)) * DHEAD + c * 8;
    f32x4 a = *(const f32x4*)src;
    f32x4 b = *(const f32x4*)(src + 4);
    o = cvt8(a, b, 1.0f);
  }
  int cp = c ^ (r & 7);
  *(s16x8*)(Ks + ((size_t)(bh * LPAD + r)) * DHEAD + cp * 8) = o;
}

// ---------------- prepass V: f32 [bh][680][64] -> bf16 V^T [bh][64][704],
// within each 64-kv tile the 4-short (8B) chunk j4 stored at j4 ^ (d&15). ----
__global__ __launch_bounds__(256) void prep_v(const float* __restrict__ Vg,
                                              short* __restrict__ Vt) {
  int bid = blockIdx.x;                          // 128 * 11 * 2
  int bh = bid / 22;
  int r2 = bid - bh * 22;
  int kvt = r2 >> 1, half = r2 & 1;
  int d = threadIdx.x & 63;
  int j = (threadIdx.x >> 6) + half * 4;         // 0..7: 8 kv each
  int kvb = kvt * 64 + j * 8;
  float v[8];
  #pragma unroll
  for (int i = 0; i < 8; ++i) {
    int kv = kvb + i;
    v[i] = (kv < L_TOK) ? Vg[((size_t)(bh * L_TOK + kv)) * DHEAD + d] : 0.0f;
  }
  s16x8 o;
  int sw = d & 1;                                // swap 8B halves if d odd
  #pragma unroll
  for (int i = 0; i < 4; ++i) {
    o[i]     = f2bf(v[sw ? 4 + i : i]);
    o[4 + i] = f2bf(v[sw ? i : 4 + i]);
  }
  int m = j ^ ((d & 15) >> 1);                   // 16B chunk position
  *(s16x8*)(Vt + ((size_t)(bh * DHEAD + d)) * LPAD + kvt * 64 + m * 8) = o;
}

// ---------------- main kernel: QBLK=64 (4 waves x 16q), KVBLK=64 dbuf ------
__global__ __launch_bounds__(256, 4) void var_attn2(
    const float* __restrict__ Qg, const short* __restrict__ Ks,
    const short* __restrict__ Vt, float* __restrict__ Og)
{
  const int tid  = threadIdx.x;
  const int lane = tid & 63, wave = tid >> 6;
  const int l15  = lane & 15, lg = lane >> 4;

  // XCD-aware remap: same-bh q-blocks contiguous per XCD, long blocks first
  int bid  = blockIdx.x;                         // 0..1407
  int bhlo = bid & 7;
  int t_   = bid >> 3;                           // 0..175
  int bhhi = t_ / 11;
  int qbi  = t_ - bhhi * 11;
  int qb   = 10 - qbi;
  int bh   = bhhi * 8 + bhlo;
  int qblk = qb * QBLK;

  __shared__ short kbuf[2][64 * DHEAD];          // 2 x 8KB, chunk16^= (r&7)
  __shared__ short vbuf[2][DHEAD * 64];          // 2 x 8KB, chunk8 ^= (d&15)

  const int qw        = qblk + wave * 16;
  const int qc        = min(qw + l15, L_TOK - 1);
  const int my_kvlen  = kv_len(qc);
  const int kv_need_w = kv_len(min(qw + 15, L_TOK - 1));
  const int nkv       = kv_len(min(qblk + QBLK - 1, L_TOK - 1));
  const int nt        = (nkv + 63) >> 6;         // always >= 2

  // Q fragments, pre-scaled by 1/sqrt(64)
  s16x8 qfrag[2];
  {
    const float* qp = Qg + ((size_t)(bh * L_TOK + qc)) * DHEAD + lg * 8;
    #pragma unroll
    for (int ks = 0; ks < 2; ++ks) {
      f32x4 a = *(const f32x4*)(qp + ks * 32);
      f32x4 b = *(const f32x4*)(qp + ks * 32 + 4);
      qfrag[ks] = cvt8(a, b, 0.125f);
    }
  }

  const short* ksb = Ks + (size_t)bh * LPAD * DHEAD;
  const short* vtb = Vt + (size_t)bh * DHEAD * LPAD;

  auto issue = [&](int kt, int buf) {
    const char* gk = (const char*)(ksb + kt * 64 * DHEAD);   // 8KB contiguous
    #pragma unroll
    for (int c = 0; c < 2; ++c) {
      int off = (wave * 2 + c) * 1024 + lane * 16;
      gload16(gk + off, (char*)&kbuf[buf][0] + off);
    }
    #pragma unroll
    for (int c = 0; c < 2; ++c) {
      int off = (wave * 2 + c) * 1024 + lane * 16;
      int d = off >> 7, cb = off & 127;
      gload16((const char*)(vtb + (size_t)d * LPAD + kt * 64) + cb,
              (char*)&vbuf[buf][0] + off);
    }
  };

  issue(0, 0);
  issue(1, 1);

  f32x4 oacc[4] = {};
  float m_run = -1e30f, l_run = 0.0f;

  for (int kt = 0; kt < nt; ++kt) {
    if (kt < nt - 1) { asm volatile("s_waitcnt vmcnt(4)" ::: "memory"); }
    else             { asm volatile("s_waitcnt vmcnt(0)" ::: "memory"); }
    __builtin_amdgcn_s_barrier();

    const int kv0 = kt * 64;
    if (kv0 < kv_need_w) {
      const short* kb = &kbuf[kt & 1][0];
      const short* vb = &vbuf[kt & 1][0];

      // ---- QK^T (swapped): sacc[t16] = S^T tile [16k x 16q] ----
      f32x4 sacc[4] = {};
      #pragma unroll
      for (int t16 = 0; t16 < 4; ++t16) {
        const int kr = t16 * 16 + l15;
        #pragma unroll
        for (int ks = 0; ks < 2; ++ks) {
          int cp = (lg + 4 * ks) ^ (kr & 7);
          s16x8 kf = *(const s16x8*)((const char*)kb + kr * 128 + cp * 16);
          sacc[t16] = __builtin_amdgcn_mfma_f32_16x16x32_bf16(kf, qfrag[ks], sacc[t16], 0, 0, 0);
        }
      }

      // ---- mask + online softmax (lane: 16 keys of query q=l15) ----
      float s[16];
      #pragma unroll
      for (int t16 = 0; t16 < 4; ++t16)
        #pragma unroll
        for (int r = 0; r < 4; ++r) {
          int key = kv0 + t16 * 16 + lg * 4 + r;
          s[t16 * 4 + r] = (key < my_kvlen) ? sacc[t16][r] : -1e30f;
        }
      float mt = s[0];
      #pragma unroll
      for (int i = 1; i < 16; ++i) mt = fmaxf(mt, s[i]);
      mt = fmaxf(mt, __shfl_xor(mt, 16));
      mt = fmaxf(mt, __shfl_xor(mt, 32));

      bool defer = __all(mt - m_run <= 8.0f);    // T13 defer-max
      float m_new = defer ? m_run : fmaxf(m_run, mt);

      float psum = 0.0f;
      short pf[16];
      #pragma unroll
      for (int i = 0; i < 16; ++i) {
        float p = __expf(s[i] - m_new);
        psum += p;
        pf[i] = f2bf(p);
      }
      psum += __shfl_xor(psum, 16);
      psum += __shfl_xor(psum, 32);

      if (defer) {
        l_run += psum;
      } else {
        float sc = __expf(m_run - m_new);
        l_run = l_run * sc + psum;
        m_run = m_new;
        float sc_q[4];
        #pragma unroll
        for (int r = 0; r < 4; ++r) sc_q[r] = __shfl(sc, lg * 4 + r);
        #pragma unroll
        for (int dt = 0; dt < 4; ++dt)
          #pragma unroll
          for (int r = 0; r < 4; ++r) oacc[dt][r] *= sc_q[r];
      }

      // ---- PV: A = P fragments (true k-layout: i<4 -> k=lg*4+i, i>=4 -> 16+lg*4+i-4)
      s16x8 pf0, pf1;
      #pragma unroll
      for (int i = 0; i < 8; ++i) { pf0[i] = pf[i]; pf1[i] = pf[8 + i]; }
      #pragma unroll
      for (int dt = 0; dt < 4; ++dt) {
        const int row = dt * 16 + l15;
        const char* vrow = (const char*)vb + row * 128;
        s16x4 a0 = *(const s16x4*)(vrow + ((lg     ) ^ l15) * 8);
        s16x4 a1 = *(const s16x4*)(vrow + ((lg +  4) ^ l15) * 8);
        s16x4 a2 = *(const s16x4*)(vrow + ((lg +  8) ^ l15) * 8);
        s16x4 a3 = *(const s16x4*)(vrow + ((lg + 12) ^ l15) * 8);
        s16x8 vf0, vf1;
        #pragma unroll
        for (int i = 0; i < 4; ++i) {
          vf0[i] = a0[i]; vf0[4 + i] = a1[i];
          vf1[i] = a2[i]; vf1[4 + i] = a3[i];
        }
        oacc[dt] = __builtin_amdgcn_mfma_f32_16x16x32_bf16(pf0, vf0, oacc[dt], 0, 0, 0);
        oacc[dt] = __builtin_amdgcn_mfma_f32_16x16x32_bf16(pf1, vf1, oacc[dt], 0, 0, 0);
      }
    }
    __builtin_amdgcn_s_barrier();
    if (kt + 2 < nt) issue(kt + 2, kt & 1);
  }

  // ---- epilogue ----
  float linv = 1.0f / l_run;
  float li_q[4];
  #pragma unroll
  for (int r = 0; r < 4; ++r) li_q[r] = __shfl(linv, lg * 4 + r);
  #pragma unroll
  for (int r = 0; r < 4; ++r) {
    int qo = qw + lg * 4 + r;
    if (qo < L_TOK) {
      float* dst = Og + ((size_t)(bh * L_TOK + qo)) * DHEAD + l15;
      #pragma unroll
      for (int dt = 0; dt < 4; ++dt) dst[dt * 16] = oacc[dt][r] * li_q[r];
    }
  }
}

// ---------------- R1 fallback kernel (known-good, f32 direct) ----------------
#define KVBLK1 32
#define VTS    36
__global__ __launch_bounds__(256, 2) void var_attn(
    const float* __restrict__ Qg, const float* __restrict__ Kg,
    const float* __restrict__ Vg, float* __restrict__ Og)
{
  const int tid  = threadIdx.x;
  const int bh   = blockIdx.y;
  const int qblk = blockIdx.x * QBLK;
  const int wave = tid >> 6;
  const int lane = tid & 63;
  const int l15  = lane & 15;
  const int lg   = lane >> 4;

  __shared__ short kbuf[KVBLK1 * DHEAD];
  __shared__ short vtbuf[DHEAD * VTS];

  const int qw   = qblk + wave * 16;
  const int qc   = min(qw + l15, L_TOK - 1);
  const int my_kvlen  = kv_len(qc);
  const int kv_need_w = kv_len(min(qw + 15, L_TOK - 1));
  const int nkv       = kv_len(min(qblk + QBLK - 1, L_TOK - 1));

  s16x8 qfrag[2];
  {
    const float* qptr = Qg + ((size_t)(bh * L_TOK + qc)) * DHEAD + lg * 8;
    #pragma unroll
    for (int ks = 0; ks < 2; ++ks) {
      f32x4 a = *(const f32x4*)(qptr + ks * 32);
      f32x4 b = *(const f32x4*)(qptr + ks * 32 + 4);
      qfrag[ks] = cvt8(a, b, 0.125f);
    }
  }

  f32x4 oacc[4] = {};
  float m_run = -1e30f, l_run = 0.0f;

  const int stage_r = tid >> 3;
  const int stage_c = (tid & 7) * 8;
  const float* kbase = Kg + (size_t)bh * L_TOK * DHEAD;
  const float* vbase = Vg + (size_t)bh * L_TOK * DHEAD;

  for (int kv0 = 0; kv0 < nkv; kv0 += KVBLK1) {
    {
      const int rsrc = min(kv0 + stage_r, L_TOK - 1);
      const float* ks_ = kbase + (size_t)rsrc * DHEAD + stage_c;
      f32x4 a = *(const f32x4*)ks_;
      f32x4 b = *(const f32x4*)(ks_ + 4);
      s16x8 kf = cvt8(a, b, 1.0f);
      int boff = (stage_r * 128 + stage_c * 2) ^ ((stage_r & 7) << 4);
      *(s16x8*)((char*)kbuf + boff) = kf;
      const float* vs_ = vbase + (size_t)rsrc * DHEAD + stage_c;
      f32x4 c = *(const f32x4*)vs_;
      f32x4 d = *(const f32x4*)(vs_ + 4);
      #pragma unroll
      for (int i = 0; i < 4; ++i) vtbuf[(stage_c + i) * VTS + stage_r] = f2bf(c[i]);
      #pragma unroll
      for (int i = 0; i < 4; ++i) vtbuf[(stage_c + 4 + i) * VTS + stage_r] = f2bf(d[i]);
    }
    __syncthreads();
    if (kv0 < kv_need_w) {
      f32x4 sacc[2] = {};
      #pragma unroll
      for (int t = 0; t < 2; ++t) {
        const int kr = t * 16 + l15;
        #pragma unroll
        for (int ks = 0; ks < 2; ++ks) {
          int boff = (kr * 128 + (lg * 8 + ks * 32) * 2) ^ ((kr & 7) << 4);
          s16x8 kf = *(const s16x8*)((char*)kbuf + boff);
          sacc[t] = __builtin_amdgcn_mfma_f32_16x16x32_bf16(kf, qfrag[ks], sacc[t], 0, 0, 0);
        }
      }
      float s[8];
      #pragma unroll
      for (int t = 0; t < 2; ++t)
        #pragma unroll
        for (int r = 0; r < 4; ++r) {
          int key = kv0 + t * 16 + lg * 4 + r;
          s[t * 4 + r] = (key < my_kvlen) ? sacc[t][r] : -1e30f;
        }
      float mt = s[0];
      #pragma unroll
      for (int i = 1; i < 8; ++i) mt = fmaxf(mt, s[i]);
      mt = fmaxf(mt, __shfl_xor(mt, 16));
      mt = fmaxf(mt, __shfl_xor(mt, 32));
      float m_new = fmaxf(m_run, mt);
      float sc = __expf(m_run - m_new);
      float psum = 0.0f;
      short pf[8];
      #pragma unroll
      for (int i = 0; i < 8; ++i) {
        float p = __expf(s[i] - m_new);
        psum += p;
        pf[i] = f2bf(p);
      }
      psum += __shfl_xor(psum, 16);
      psum += __shfl_xor(psum, 32);
      l_run = l_run * sc + psum;
      m_run = m_new;
      float sc_q[4];
      #pragma unroll
      for (int r = 0; r < 4; ++r) sc_q[r] = __shfl(sc, lg * 4 + r);
      #pragma unroll
      for (int dt = 0; dt < 4; ++dt)
        #pragma unroll
        for (int r = 0; r < 4; ++r) oacc[dt][r] *= sc_q[r];
      s16x8 pfrag;
      #pragma unroll
      for (int i = 0; i < 8; ++i) pfrag[i] = pf[i];
      #pragma unroll
      for (int dt = 0; dt < 4; ++dt) {
        const short* row = vtbuf + (dt * 16 + l15) * VTS + lg * 4;
        s16x4 v0 = *(const s16x4*)row;
        s16x4 v1 = *(const s16x4*)(row + 16);
        s16x8 vf;
        vf[0] = v0[0]; vf[1] = v0[1]; vf[2] = v0[2]; vf[3] = v0[3];
        vf[4] = v1[0]; vf[5] = v1[1]; vf[6] = v1[2]; vf[7] = v1[3];
        oacc[dt] = __builtin_amdgcn_mfma_f32_16x16x32_bf16(pfrag, vf, oacc[dt], 0, 0, 0);
      }
    }
    __syncthreads();
  }

  float linv = 1.0f / l_run;
  float li_q[4];
  #pragma unroll
  for (int r = 0; r < 4; ++r) li_q[r] = __shfl(linv, lg * 4 + r);
  #pragma unroll
  for (int r = 0; r < 4; ++r) {
    int qo = qw + lg * 4 + r;
    if (qo < L_TOK) {
      float* dst = Og + ((size_t)(bh * L_TOK + qo)) * DHEAD + l15;
      #pragma unroll
      for (int dt = 0; dt < 4; ++dt) dst[dt * 16] = oacc[dt][r] * li_q[r];
    }
  }
}

extern "C" void kernel_launch(void* const* d_in, const int* in_sizes, int n_in,
                              void* d_out, int out_size, void* d_ws, size_t ws_size,
                              hipStream_t stream) {
  const float* q = (const float*)d_in[0];
  const float* k = (const float*)d_in[1];
  const float* v = (const float*)d_in[2];
  float* o = (float*)d_out;

  const size_t ksz  = (size_t)NBH * LPAD * DHEAD;     // shorts
  const size_t need = 2 * ksz * sizeof(short);        // Ks + Vt = 23.1 MB
  if (ws_size >= need) {
    short* Ks = (short*)d_ws;
    short* Vt = Ks + ksz;
    prep_k<<<2816, 256, 0, stream>>>(k, Ks);
    prep_v<<<2816, 256, 0, stream>>>(v, Vt);
    var_attn2<<<1408, 256, 0, stream>>>(q, Ks, Vt, o);
  } else {
    dim3 grid((L_TOK + QBLK - 1) / QBLK, NBH);
    var_attn<<<grid, 256, 0, stream>>>(q, k, v, o);
  }
}